// Round 2
// baseline (404.868 us; speedup 1.0000x reference)
//
#include <hip/hip_runtime.h>
#include <math.h>

// TGV-2 PDHG, B=2, H=W=256, T=128.
// R15: wave-autonomous trapezoids — ZERO barriers, ZERO LDS arrays.
// R14 post-mortem: trapezoid gating (skip 18% of wave-iters) was NEUTRAL and
// R12 (fewer DS ops) was neutral -> per-iter cost is the serial path
// ds_write -> 12-wave barrier+drain -> ds_read latency -> dep VALU -> barrier,
// ~1.3us/iter vs ~0.2us pure issue. Nothing inside that structure fixes it.
// R15 removes the structure: rows live in LANES (lane = r + 32*half), columns
// live in REGISTERS (12 cols = 6 v2f per field per lane). Neighbor exchange:
//   vertical   (dual: down ub/vb1/vb2, primal: up p1/q11/q12) = __shfl +-1
//   horizontal = in-register element shifts + 6 scalar __shfl_xor(32) at the
//                col-half boundary (col 11<->12)
// Each wave independently owns a 32x24 region -> 16x8 output (halo 8), so a
// launch of 1024 waves (256 blocks x 256 thr, 1 wave/SIMD machine-wide) runs
// 8 iterations with no synchronization at all. Redundancy 3.0 -> 6.0, but
// total VALU issue for all 128 iters is only ~52us machine-wide; the removed
// barrier/LDS latency was ~2000cyc/iter. Per-pixel math is op-identical to
// R9/R14 (same masks, formulas, order) -> same absmax. Region-rim pixels
// evolve garbage-but-finite values (projections bound p,q; u,v contract) and
// are never read by valid outputs (ring-per-iter trapezoid, halo 8 = iters).
// 16 launches x 8 iters as before; init folded into launch 0; final launch
// stores only u.

namespace {

typedef float v2f __attribute__((ext_vector_type(2)));

constexpr int kN = 2 * 256 * 256;
constexpr float kTau = 0.28867513459481287f;  // 1/sqrt(12) (f32)
constexpr float kSigma = kTau;
constexpr float kInv1pTau = 1.0f / (1.0f + kTau);

constexpr int HALO = 8;                  // iterations per launch
constexpr int NLAUNCH = 128 / HALO;      // 16

__device__ __forceinline__ float4 ld4(const float* p) {
  return *reinterpret_cast<const float4*>(p);
}

__device__ __forceinline__ v2f mk2(float x, float y) {
  v2f r;
  r.x = x;
  r.y = y;
  return r;
}

__device__ __forceinline__ v2f shdn(v2f x) {  // lane i <- lane i+1 (row r+1)
  v2f y;
  y.x = __shfl_down(x.x, 1);
  y.y = __shfl_down(x.y, 1);
  return y;
}

__device__ __forceinline__ v2f shup(v2f x) {  // lane i <- lane i-1 (row r-1)
  v2f y;
  y.x = __shfl_up(x.x, 1);
  y.y = __shfl_up(x.y, 1);
  return y;
}

// ws layout: 10 arrays of kN floats: ub, v1, v2, vb1, vb2, p1, p2, q11, q22, q12
__global__ __launch_bounds__(256, 1) void tgv_wave_kernel(
    const float* __restrict__ f, const float* __restrict__ rp,
    float* __restrict__ ug, float* __restrict__ ws, int t0) {
  float* ubg = ws + 0 * kN;
  float* v1g = ws + 1 * kN;
  float* v2g = ws + 2 * kN;
  float* vb1g = ws + 3 * kN;
  float* vb2g = ws + 4 * kN;
  float* p1g = ws + 5 * kN;
  float* p2g = ws + 6 * kN;
  float* q11g = ws + 7 * kN;
  float* q22g = ws + 8 * kN;
  float* q12g = ws + 9 * kN;

  const int tid = threadIdx.x;
  const int wave = tid >> 6;
  const int lane = tid & 63;
  const int r = lane & 31;    // region row 0..31 (lanes!)
  const int half = lane >> 5; // column half: 0 -> cols 0..11, 1 -> cols 12..23

  const int band = blockIdx.y;               // 0..15 row band
  const int colblk = blockIdx.x * 4 + wave;  // 0..31 col block
  const int batch = blockIdx.z;

  const int gi = band * 16 + r - HALO;              // global row of this lane
  const int gj0 = colblk * 8 - HALO + half * 12;    // lane's first global col
  const bool rowOK = ((unsigned)gi < 256u);
  const int base = batch * 65536 + gi * 256 + gj0;  // may be <0; never deref'd OOB

  const float alpha0 = rp[0];
  const float alpha1 = rp[1];

  // ---- boundary masks as 0/1 multipliers ----
  const float mD = (gi != 255) ? 1.f : 0.f;  // has down neighbor
  const float mU = (gi != 0) ? 1.f : 0.f;    // has up neighbor
  v2f mR[6], mL[6];
#pragma unroll
  for (int k = 0; k < 6; ++k) {
    const int c0 = gj0 + 2 * k;
    mR[k].x = (c0 != 255) ? 1.f : 0.f;
    mR[k].y = (c0 + 1 != 255) ? 1.f : 0.f;
    mL[k].x = (c0 != 0) ? 1.f : 0.f;
    mL[k].y = 1.f;  // odd global col, never 0
  }

  // ---- per-lane state: 12 cols as 6 v2f strips per field ----
  v2f u_[6], ub_[6], v1_[6], v2_[6], vb1_[6], vb2_[6];
  v2f p1_[6], p2_[6], q11_[6], q22_[6], q12_[6], f_[6];
#pragma unroll
  for (int k = 0; k < 6; ++k) {
    u_[k] = 0.f; ub_[k] = 0.f; v1_[k] = 0.f; v2_[k] = 0.f;
    vb1_[k] = 0.f; vb2_[k] = 0.f; p1_[k] = 0.f; p2_[k] = 0.f;
    q11_[k] = 0.f; q22_[k] = 0.f; q12_[k] = 0.f; f_[k] = 0.f;
  }

  // 3 aligned float4 column-groups per field; image-edge groups masked.
  const bool ok0 = rowOK && (gj0 >= 0) && (gj0 < 256);
  const bool ok1 = rowOK && (gj0 + 4 >= 0) && (gj0 + 4 < 256);
  const bool ok2 = rowOK && (gj0 + 8 >= 0) && (gj0 + 8 < 256);

  if (t0 == 0) {
    float4 a;
    if (ok0) { a = ld4(f + base + 0); f_[0] = mk2(a.x, a.y); f_[1] = mk2(a.z, a.w); }
    if (ok1) { a = ld4(f + base + 4); f_[2] = mk2(a.x, a.y); f_[3] = mk2(a.z, a.w); }
    if (ok2) { a = ld4(f + base + 8); f_[4] = mk2(a.x, a.y); f_[5] = mk2(a.z, a.w); }
#pragma unroll
    for (int k = 0; k < 6; ++k) { u_[k] = f_[k]; ub_[k] = f_[k]; }
  } else {
#define LDJ(J, K)                                                             \
  {                                                                           \
    float4 a;                                                                 \
    a = ld4(f + base + J);    f_[K] = mk2(a.x, a.y);   f_[K + 1] = mk2(a.z, a.w);   \
    a = ld4(ug + base + J);   u_[K] = mk2(a.x, a.y);   u_[K + 1] = mk2(a.z, a.w);   \
    a = ld4(ubg + base + J);  ub_[K] = mk2(a.x, a.y);  ub_[K + 1] = mk2(a.z, a.w);  \
    a = ld4(v1g + base + J);  v1_[K] = mk2(a.x, a.y);  v1_[K + 1] = mk2(a.z, a.w);  \
    a = ld4(v2g + base + J);  v2_[K] = mk2(a.x, a.y);  v2_[K + 1] = mk2(a.z, a.w);  \
    a = ld4(vb1g + base + J); vb1_[K] = mk2(a.x, a.y); vb1_[K + 1] = mk2(a.z, a.w); \
    a = ld4(vb2g + base + J); vb2_[K] = mk2(a.x, a.y); vb2_[K + 1] = mk2(a.z, a.w); \
    a = ld4(p1g + base + J);  p1_[K] = mk2(a.x, a.y);  p1_[K + 1] = mk2(a.z, a.w);  \
    a = ld4(p2g + base + J);  p2_[K] = mk2(a.x, a.y);  p2_[K + 1] = mk2(a.z, a.w);  \
    a = ld4(q11g + base + J); q11_[K] = mk2(a.x, a.y); q11_[K + 1] = mk2(a.z, a.w); \
    a = ld4(q22g + base + J); q22_[K] = mk2(a.x, a.y); q22_[K + 1] = mk2(a.z, a.w); \
    a = ld4(q12g + base + J); q12_[K] = mk2(a.x, a.y); q12_[K + 1] = mk2(a.z, a.w); \
  }
    if (ok0) LDJ(0, 0)
    if (ok1) LDJ(4, 2)
    if (ok2) LDJ(8, 4)
#undef LDJ
  }

#pragma unroll 1
  for (int t = 0; t < HALO; ++t) {
    // ---- vertical neighbors for dual: row r+1 of ub, vb1, vb2 ----
    v2f ubD[6], vb1D[6], vb2D[6];
#pragma unroll
    for (int k = 0; k < 6; ++k) {
      ubD[k] = shdn(ub_[k]);
      vb1D[k] = shdn(vb1_[k]);
      vb2D[k] = shdn(vb2_[k]);
    }
    // cross-half right-edge scalars: my col 11's right neighbor = partner col 12
    const float ubX = __shfl_xor(ub_[0].x, 32);
    const float vb1X = __shfl_xor(vb1_[0].x, 32);
    const float vb2X = __shfl_xor(vb2_[0].x, 32);

    // ---- dual ascent + projections, per strip ----
#pragma unroll
    for (int k = 0; k < 6; ++k) {
      v2f ubr, vb1r, vb2r;  // right-shifted (col c+1)
      ubr.x = ub_[k].y;   ubr.y = (k < 5) ? ub_[k + 1].x : ubX;
      vb1r.x = vb1_[k].y; vb1r.y = (k < 5) ? vb1_[k + 1].x : vb1X;
      vb2r.x = vb2_[k].y; vb2r.y = (k < 5) ? vb2_[k + 1].x : vb2X;

      // p update
      const v2f du1 = mD * (ubD[k] - ub_[k]);
      const v2f du2 = mR[k] * (ubr - ub_[k]);
      const v2f pn1 = p1_[k] + kSigma * (du1 - vb1_[k]);
      const v2f pn2 = p2_[k] + kSigma * (du2 - vb2_[k]);
      const v2f n2p = pn1 * pn1 + pn2 * pn2;
      v2f sp;
      sp.x = fminf(1.f, alpha1 * __builtin_amdgcn_rsqf(n2p.x));
      sp.y = fminf(1.f, alpha1 * __builtin_amdgcn_rsqf(n2p.y));
      p1_[k] = pn1 * sp;
      p2_[k] = pn2 * sp;

      // q update (e11, e22, e12)
      const v2f e11 = mD * (vb1D[k] - vb1_[k]);
      const v2f e22 = mR[k] * (vb2r - vb2_[k]);
      const v2f e12 = 0.5f * (mR[k] * (vb1r - vb1_[k]) + mD * (vb2D[k] - vb2_[k]));
      const v2f qn1 = q11_[k] + kSigma * e11;
      const v2f qn2 = q22_[k] + kSigma * e22;
      const v2f qn3 = q12_[k] + kSigma * e12;
      const v2f n2q = qn1 * qn1 + qn2 * qn2 + 2.f * (qn3 * qn3);
      v2f sq;
      sq.x = fminf(1.f, alpha0 * __builtin_amdgcn_rsqf(n2q.x));
      sq.y = fminf(1.f, alpha0 * __builtin_amdgcn_rsqf(n2q.y));
      q11_[k] = qn1 * sq;
      q22_[k] = qn2 * sq;
      q12_[k] = qn3 * sq;
    }

    // ---- vertical neighbors for primal: row r-1 of new p1, q11, q12 ----
    v2f p1U[6], q11U[6], q12U[6];
#pragma unroll
    for (int k = 0; k < 6; ++k) {
      p1U[k] = shup(p1_[k]);
      q11U[k] = shup(q11_[k]);
      q12U[k] = shup(q12_[k]);
    }
    // cross-half left-edge scalars: my col 12's left neighbor = partner col 11
    const float p2X = __shfl_xor(p2_[5].y, 32);
    const float q22X = __shfl_xor(q22_[5].y, 32);
    const float q12X = __shfl_xor(q12_[5].y, 32);

    // ---- primal descent + over-relaxation, per strip ----
#pragma unroll
    for (int k = 0; k < 6; ++k) {
      v2f p2l, q22l, q12l;  // left-shifted (col c-1)
      p2l.x = (k > 0) ? p2_[k - 1].y : p2X;    p2l.y = p2_[k].x;
      q22l.x = (k > 0) ? q22_[k - 1].y : q22X; q22l.y = q22_[k].x;
      q12l.x = (k > 0) ? q12_[k - 1].y : q12X; q12l.y = q12_[k].x;

      const v2f divp = mD * p1_[k] + mR[k] * p2_[k] - (mU * p1U[k] + mL[k] * p2l);
      const v2f un = (u_[k] + kTau * divp + kTau * f_[k]) * kInv1pTau;
      ub_[k] = 2.f * un - u_[k];
      u_[k] = un;

      const v2f c1 = mD * q11_[k] + mR[k] * q12_[k] - (mU * q11U[k] + mL[k] * q12l);
      const v2f c2 = mD * q12_[k] + mR[k] * q22_[k] - (mU * q12U[k] + mL[k] * q22l);
      const v2f v1n = v1_[k] + kTau * (p1_[k] + c1);
      const v2f v2n = v2_[k] + kTau * (p2_[k] + c2);
      vb1_[k] = 2.f * v1n - v1_[k];
      v1_[k] = v1n;
      vb2_[k] = 2.f * v2n - v2_[k];
      v2_[k] = v2n;
    }
  }

  // ---- store: valid rows r in [8,24); valid cols are 4 per lane:
  //  half 0 -> local cols 8..11 (strips 4,5), half 1 -> local cols 0..3 (strips 0,1)
  if (r >= HALO && r < HALO + 16) {
    const int obase = batch * 65536 + gi * 256 + (colblk * 8 + half * 4);
    const bool storeWs = (t0 != NLAUNCH - 1);  // ws dead after final launch
    if (half == 0) {
#define ST(arr, dst)                                              \
  {                                                               \
    float4 o;                                                     \
    o.x = arr[4].x; o.y = arr[4].y; o.z = arr[5].x; o.w = arr[5].y; \
    *reinterpret_cast<float4*>((dst) + obase) = o;                \
  }
      ST(u_, ug)
      if (storeWs) {
        ST(ub_, ubg) ST(v1_, v1g) ST(v2_, v2g) ST(vb1_, vb1g) ST(vb2_, vb2g)
        ST(p1_, p1g) ST(p2_, p2g) ST(q11_, q11g) ST(q22_, q22g) ST(q12_, q12g)
      }
#undef ST
    } else {
#define ST(arr, dst)                                              \
  {                                                               \
    float4 o;                                                     \
    o.x = arr[0].x; o.y = arr[0].y; o.z = arr[1].x; o.w = arr[1].y; \
    *reinterpret_cast<float4*>((dst) + obase) = o;                \
  }
      ST(u_, ug)
      if (storeWs) {
        ST(ub_, ubg) ST(v1_, v1g) ST(v2_, v2g) ST(vb1_, vb1g) ST(vb2_, vb2g)
        ST(p1_, p1g) ST(p2_, p2g) ST(q11_, q11g) ST(q22_, q22g) ST(q12_, q12g)
      }
#undef ST
    }
  }
}

}  // namespace

extern "C" void kernel_launch(void* const* d_in, const int* in_sizes, int n_in,
                              void* d_out, int out_size, void* d_ws,
                              size_t ws_size, hipStream_t stream) {
  const float* f = (const float*)d_in[0];
  const float* rp = (const float*)d_in[1];  // [alpha0, alpha1]
  // d_in[2] is T = 128 (fixed; trip count must be static for graph capture).

  float* u = (float*)d_out;
  float* ws = (float*)d_ws;

  // 16 row-bands x 8 col-block-groups x 2 batches; 4 waves/block = 4 colblks.
  dim3 grid(8, 16, 2);  // 256 blocks, 1/CU; 1024 autonomous waves, 1/SIMD
  for (int t = 0; t < NLAUNCH; ++t) {
    hipLaunchKernelGGL(tgv_wave_kernel, grid, dim3(256), 0, stream, f, rp, u,
                       ws, t);
  }
}

// Round 4
// 350.190 us; speedup vs baseline: 1.1561x; 1.1561x over previous
//
#include <hip/hip_runtime.h>
#include <math.h>

// TGV-2 PDHG, B=2, H=W=256, T=128.
// R17 = R16 resubmitted verbatim (R16's bench died with "MI355X container
// failed twice" — infra flake, no compile/correctness signal; kernel audit
// found no hang vectors: static trip counts, guarded loads/stores, legal
// GFX9 DPP controls, no graph-capture violations).
// R16 rationale: R15 (wave-autonomous trapezoids, zero barriers, zero LDS
// arrays) was correct (absmax 7.45e-9) but slow (405us): __shfl_up/down are
// ds_bpermute_b32 (LDS pipe, ~60-100cyc), 78/iter on the critical path with
// 1 wave/SIMD -> nothing hides them. R16 replaces the 72 +-1-lane shifts
// with DPP v_mov_b32_dpp wave_shr:1 / wave_shl:1 — single VALU ops, no LDS
// pipe. Direction (AMD DPP scan idiom): wave_shr:1 -> lane i reads lane i-1
// (shup); wave_shl:1 -> lane i reads lane i+1 (shdn). Boundary-lane
// contamination lands only on region rows r=0/r=31 — never read by valid
// trapezoid outputs (validated by R15's passing absmax). The 6 remaining
// cross-half scalars stay __shfl_xor(,32) (bpermute) but are issued 5
// independent strips (~250cyc) ahead of their single consumer: dual consumes
// at k=5; primal strip order {1..5,0} puts its consumer last.
// Layout: rows in LANES (lane = r + 32*half), 12 cols in REGISTERS (6 v2f
// strips per field). Wave region 32x24 -> output 16x8, 1024 waves = 1/SIMD
// machine-wide. Per-pixel math op-identical to R9.
// 16 launches x 8 iters; init folded into launch 0; final launch stores u only.

namespace {

typedef float v2f __attribute__((ext_vector_type(2)));

constexpr int kN = 2 * 256 * 256;
constexpr float kTau = 0.28867513459481287f;  // 1/sqrt(12) (f32)
constexpr float kSigma = kTau;
constexpr float kInv1pTau = 1.0f / (1.0f + kTau);

constexpr int HALO = 8;                  // iterations per launch
constexpr int NLAUNCH = 128 / HALO;      // 16

__device__ __forceinline__ float4 ld4(const float* p) {
  return *reinterpret_cast<const float4*>(p);
}

__device__ __forceinline__ v2f mk2(float x, float y) {
  v2f r;
  r.x = x;
  r.y = y;
  return r;
}

// DPP lane shift, single VALU op. CTRL: 0x130 = wave_shl:1 (lane i <- i+1),
// 0x138 = wave_shr:1 (lane i <- i-1). bound_ctrl=1 -> invalid lanes read 0.
template <int CTRL>
__device__ __forceinline__ float dppf(float x) {
  return __builtin_bit_cast(
      float, __builtin_amdgcn_update_dpp(0, __builtin_bit_cast(int, x), CTRL,
                                         0xF, 0xF, true));
}

template <int CTRL>
__device__ __forceinline__ v2f dpp2(v2f x) {
  v2f y;
  y.x = dppf<CTRL>(x.x);
  y.y = dppf<CTRL>(x.y);
  return y;
}

__device__ __forceinline__ v2f shdn(v2f x) { return dpp2<0x130>(x); }  // row r+1
__device__ __forceinline__ v2f shup(v2f x) { return dpp2<0x138>(x); }  // row r-1

// ws layout: 10 arrays of kN floats: ub, v1, v2, vb1, vb2, p1, p2, q11, q22, q12
__global__ __launch_bounds__(256, 1) void tgv_wave_kernel(
    const float* __restrict__ f, const float* __restrict__ rp,
    float* __restrict__ ug, float* __restrict__ ws, int t0) {
  float* ubg = ws + 0 * kN;
  float* v1g = ws + 1 * kN;
  float* v2g = ws + 2 * kN;
  float* vb1g = ws + 3 * kN;
  float* vb2g = ws + 4 * kN;
  float* p1g = ws + 5 * kN;
  float* p2g = ws + 6 * kN;
  float* q11g = ws + 7 * kN;
  float* q22g = ws + 8 * kN;
  float* q12g = ws + 9 * kN;

  const int tid = threadIdx.x;
  const int wave = tid >> 6;
  const int lane = tid & 63;
  const int r = lane & 31;    // region row 0..31 (lanes!)
  const int half = lane >> 5; // column half: 0 -> cols 0..11, 1 -> cols 12..23

  const int band = blockIdx.y;               // 0..15 row band
  const int colblk = blockIdx.x * 4 + wave;  // 0..31 col block
  const int batch = blockIdx.z;

  const int gi = band * 16 + r - HALO;              // global row of this lane
  const int gj0 = colblk * 8 - HALO + half * 12;    // lane's first global col
  const bool rowOK = ((unsigned)gi < 256u);
  const int base = batch * 65536 + gi * 256 + gj0;  // may be <0; never deref'd OOB

  const float alpha0 = rp[0];
  const float alpha1 = rp[1];

  // ---- boundary masks as 0/1 multipliers ----
  const float mD = (gi != 255) ? 1.f : 0.f;  // has down neighbor
  const float mU = (gi != 0) ? 1.f : 0.f;    // has up neighbor
  v2f mR[6], mL[6];
#pragma unroll
  for (int k = 0; k < 6; ++k) {
    const int c0 = gj0 + 2 * k;
    mR[k].x = (c0 != 255) ? 1.f : 0.f;
    mR[k].y = (c0 + 1 != 255) ? 1.f : 0.f;
    mL[k].x = (c0 != 0) ? 1.f : 0.f;
    mL[k].y = 1.f;  // odd global col, never 0
  }

  // ---- per-lane state: 12 cols as 6 v2f strips per field ----
  v2f u_[6], ub_[6], v1_[6], v2_[6], vb1_[6], vb2_[6];
  v2f p1_[6], p2_[6], q11_[6], q22_[6], q12_[6], f_[6];
#pragma unroll
  for (int k = 0; k < 6; ++k) {
    u_[k] = 0.f; ub_[k] = 0.f; v1_[k] = 0.f; v2_[k] = 0.f;
    vb1_[k] = 0.f; vb2_[k] = 0.f; p1_[k] = 0.f; p2_[k] = 0.f;
    q11_[k] = 0.f; q22_[k] = 0.f; q12_[k] = 0.f; f_[k] = 0.f;
  }

  // 3 aligned float4 column-groups per field; image-edge groups masked.
  const bool ok0 = rowOK && (gj0 >= 0) && (gj0 < 256);
  const bool ok1 = rowOK && (gj0 + 4 >= 0) && (gj0 + 4 < 256);
  const bool ok2 = rowOK && (gj0 + 8 >= 0) && (gj0 + 8 < 256);

  if (t0 == 0) {
    float4 a;
    if (ok0) { a = ld4(f + base + 0); f_[0] = mk2(a.x, a.y); f_[1] = mk2(a.z, a.w); }
    if (ok1) { a = ld4(f + base + 4); f_[2] = mk2(a.x, a.y); f_[3] = mk2(a.z, a.w); }
    if (ok2) { a = ld4(f + base + 8); f_[4] = mk2(a.x, a.y); f_[5] = mk2(a.z, a.w); }
#pragma unroll
    for (int k = 0; k < 6; ++k) { u_[k] = f_[k]; ub_[k] = f_[k]; }
  } else {
#define LDJ(J, K)                                                             \
  {                                                                           \
    float4 a;                                                                 \
    a = ld4(f + base + J);    f_[K] = mk2(a.x, a.y);   f_[K + 1] = mk2(a.z, a.w);   \
    a = ld4(ug + base + J);   u_[K] = mk2(a.x, a.y);   u_[K + 1] = mk2(a.z, a.w);   \
    a = ld4(ubg + base + J);  ub_[K] = mk2(a.x, a.y);  ub_[K + 1] = mk2(a.z, a.w);  \
    a = ld4(v1g + base + J);  v1_[K] = mk2(a.x, a.y);  v1_[K + 1] = mk2(a.z, a.w);  \
    a = ld4(v2g + base + J);  v2_[K] = mk2(a.x, a.y);  v2_[K + 1] = mk2(a.z, a.w);  \
    a = ld4(vb1g + base + J); vb1_[K] = mk2(a.x, a.y); vb1_[K + 1] = mk2(a.z, a.w); \
    a = ld4(vb2g + base + J); vb2_[K] = mk2(a.x, a.y); vb2_[K + 1] = mk2(a.z, a.w); \
    a = ld4(p1g + base + J);  p1_[K] = mk2(a.x, a.y);  p1_[K + 1] = mk2(a.z, a.w);  \
    a = ld4(p2g + base + J);  p2_[K] = mk2(a.x, a.y);  p2_[K + 1] = mk2(a.z, a.w);  \
    a = ld4(q11g + base + J); q11_[K] = mk2(a.x, a.y); q11_[K + 1] = mk2(a.z, a.w); \
    a = ld4(q22g + base + J); q22_[K] = mk2(a.x, a.y); q22_[K + 1] = mk2(a.z, a.w); \
    a = ld4(q12g + base + J); q12_[K] = mk2(a.x, a.y); q12_[K + 1] = mk2(a.z, a.w); \
  }
    if (ok0) LDJ(0, 0)
    if (ok1) LDJ(4, 2)
    if (ok2) LDJ(8, 4)
#undef LDJ
  }

#pragma unroll 1
  for (int t = 0; t < HALO; ++t) {
    // cross-half right-edge scalars (bpermute): issued here, consumed only at
    // dual strip k=5 — 5 strips (~250cyc) of independent math hide the latency
    const float ubX = __shfl_xor(ub_[0].x, 32);
    const float vb1X = __shfl_xor(vb1_[0].x, 32);
    const float vb2X = __shfl_xor(vb2_[0].x, 32);

    // ---- dual ascent + projections, strips k=0..5 ----
#pragma unroll
    for (int k = 0; k < 6; ++k) {
      const v2f ubD = shdn(ub_[k]);     // row r+1, single VALU DPP
      const v2f vb1D = shdn(vb1_[k]);
      const v2f vb2D = shdn(vb2_[k]);

      v2f ubr, vb1r, vb2r;  // right-shifted (col c+1)
      ubr.x = ub_[k].y;   ubr.y = (k < 5) ? ub_[k + 1].x : ubX;
      vb1r.x = vb1_[k].y; vb1r.y = (k < 5) ? vb1_[k + 1].x : vb1X;
      vb2r.x = vb2_[k].y; vb2r.y = (k < 5) ? vb2_[k + 1].x : vb2X;

      // p update
      const v2f du1 = mD * (ubD - ub_[k]);
      const v2f du2 = mR[k] * (ubr - ub_[k]);
      const v2f pn1 = p1_[k] + kSigma * (du1 - vb1_[k]);
      const v2f pn2 = p2_[k] + kSigma * (du2 - vb2_[k]);
      const v2f n2p = pn1 * pn1 + pn2 * pn2;
      v2f sp;
      sp.x = fminf(1.f, alpha1 * __builtin_amdgcn_rsqf(n2p.x));
      sp.y = fminf(1.f, alpha1 * __builtin_amdgcn_rsqf(n2p.y));
      p1_[k] = pn1 * sp;
      p2_[k] = pn2 * sp;

      // q update (e11, e22, e12)
      const v2f e11 = mD * (vb1D - vb1_[k]);
      const v2f e22 = mR[k] * (vb2r - vb2_[k]);
      const v2f e12 = 0.5f * (mR[k] * (vb1r - vb1_[k]) + mD * (vb2D - vb2_[k]));
      const v2f qn1 = q11_[k] + kSigma * e11;
      const v2f qn2 = q22_[k] + kSigma * e22;
      const v2f qn3 = q12_[k] + kSigma * e12;
      const v2f n2q = qn1 * qn1 + qn2 * qn2 + 2.f * (qn3 * qn3);
      v2f sq;
      sq.x = fminf(1.f, alpha0 * __builtin_amdgcn_rsqf(n2q.x));
      sq.y = fminf(1.f, alpha0 * __builtin_amdgcn_rsqf(n2q.y));
      q11_[k] = qn1 * sq;
      q22_[k] = qn2 * sq;
      q12_[k] = qn3 * sq;
    }

    // cross-half left-edge scalars (bpermute): consumed only at primal strip
    // k=0, which runs LAST below — latency hidden by 5 strips of math
    const float p2X = __shfl_xor(p2_[5].y, 32);
    const float q22X = __shfl_xor(q22_[5].y, 32);
    const float q12X = __shfl_xor(q12_[5].y, 32);

    // ---- primal descent + over-relaxation, strip order {1,2,3,4,5,0} ----
    constexpr int ord[6] = {1, 2, 3, 4, 5, 0};
#pragma unroll
    for (int kk = 0; kk < 6; ++kk) {
      const int k = ord[kk];
      const v2f p1U = shup(p1_[k]);     // row r-1, single VALU DPP
      const v2f q11U = shup(q11_[k]);
      const v2f q12U = shup(q12_[k]);

      v2f p2l, q22l, q12l;  // left-shifted (col c-1)
      p2l.x = (k > 0) ? p2_[k - 1].y : p2X;    p2l.y = p2_[k].x;
      q22l.x = (k > 0) ? q22_[k - 1].y : q22X; q22l.y = q22_[k].x;
      q12l.x = (k > 0) ? q12_[k - 1].y : q12X; q12l.y = q12_[k].x;

      const v2f divp = mD * p1_[k] + mR[k] * p2_[k] - (mU * p1U + mL[k] * p2l);
      const v2f un = (u_[k] + kTau * divp + kTau * f_[k]) * kInv1pTau;
      ub_[k] = 2.f * un - u_[k];
      u_[k] = un;

      const v2f c1 = mD * q11_[k] + mR[k] * q12_[k] - (mU * q11U + mL[k] * q12l);
      const v2f c2 = mD * q12_[k] + mR[k] * q22_[k] - (mU * q12U + mL[k] * q22l);
      const v2f v1n = v1_[k] + kTau * (p1_[k] + c1);
      const v2f v2n = v2_[k] + kTau * (p2_[k] + c2);
      vb1_[k] = 2.f * v1n - v1_[k];
      v1_[k] = v1n;
      vb2_[k] = 2.f * v2n - v2_[k];
      v2_[k] = v2n;
    }
  }

  // ---- store: valid rows r in [8,24); valid cols are 4 per lane:
  //  half 0 -> local cols 8..11 (strips 4,5), half 1 -> local cols 0..3 (strips 0,1)
  if (r >= HALO && r < HALO + 16) {
    const int obase = batch * 65536 + gi * 256 + (colblk * 8 + half * 4);
    const bool storeWs = (t0 != NLAUNCH - 1);  // ws dead after final launch
    if (half == 0) {
#define ST(arr, dst)                                              \
  {                                                               \
    float4 o;                                                     \
    o.x = arr[4].x; o.y = arr[4].y; o.z = arr[5].x; o.w = arr[5].y; \
    *reinterpret_cast<float4*>((dst) + obase) = o;                \
  }
      ST(u_, ug)
      if (storeWs) {
        ST(ub_, ubg) ST(v1_, v1g) ST(v2_, v2g) ST(vb1_, vb1g) ST(vb2_, vb2g)
        ST(p1_, p1g) ST(p2_, p2g) ST(q11_, q11g) ST(q22_, q22g) ST(q12_, q12g)
      }
#undef ST
    } else {
#define ST(arr, dst)                                              \
  {                                                               \
    float4 o;                                                     \
    o.x = arr[0].x; o.y = arr[0].y; o.z = arr[1].x; o.w = arr[1].y; \
    *reinterpret_cast<float4*>((dst) + obase) = o;                \
  }
      ST(u_, ug)
      if (storeWs) {
        ST(ub_, ubg) ST(v1_, v1g) ST(v2_, v2g) ST(vb1_, vb1g) ST(vb2_, vb2g)
        ST(p1_, p1g) ST(p2_, p2g) ST(q11_, q11g) ST(q22_, q22g) ST(q12_, q12g)
      }
#undef ST
    }
  }
}

}  // namespace

extern "C" void kernel_launch(void* const* d_in, const int* in_sizes, int n_in,
                              void* d_out, int out_size, void* d_ws,
                              size_t ws_size, hipStream_t stream) {
  const float* f = (const float*)d_in[0];
  const float* rp = (const float*)d_in[1];  // [alpha0, alpha1]
  // d_in[2] is T = 128 (fixed; trip count must be static for graph capture).

  float* u = (float*)d_out;
  float* ws = (float*)d_ws;

  // 16 row-bands x 8 col-block-groups x 2 batches; 4 waves/block = 4 colblks.
  dim3 grid(8, 16, 2);  // 256 blocks, 1/CU; 1024 autonomous waves, 1/SIMD
  for (int t = 0; t < NLAUNCH; ++t) {
    hipLaunchKernelGGL(tgv_wave_kernel, grid, dim3(256), 0, stream, f, rp, u,
                       ws, t);
  }
}

// Round 5
// 324.353 us; speedup vs baseline: 1.2482x; 1.0797x over previous
//
#include <hip/hip_runtime.h>
#include <math.h>

// TGV-2 PDHG, B=2, H=W=256, T=128.
// R18 = R17 (wave-autonomous trapezoids, DPP row shifts, zero barriers) with
// the I/O fixed. R17 post-mortem: common term across R15/R17 ~17us/dispatch =
// UNCOALESCED global I/O. lane=row layout -> consecutive lanes read addresses
// 1KB apart -> every global_load_dwordx4 touches 64 distinct cache lines
// (~150MB of line traffic/dispatch). Compute (DPP) was only ~5us.
// Fix: coalesced loads (lane walks rows) + per-wave LDS transpose into the
// lane=row register layout. ZERO barriers still: all LDS exchange is within
// one wave, and DS ops of a wave execute in order (standard intra-wave LDS
// idiom, compiler inserts the lgkmcnt waits). Stores transposed likewise.
// LDS buffer: 32 rows x stride 28 floats (16B-aligned rows; worst 4-way read
// conflict ~ 1.58x on 72 ds_read_b64 only). Loads issued in 3 groups of 12
// float4 for MLP. Iteration loop untouched from R17 -> valid-pixel math
// bit-identical (absmax 7.45e-9 in R15/R17).
// Layout: rows in LANES (lane = r + 32*half), 12 cols in REGISTERS (6 v2f
// strips/field). Wave region 32x24 -> output 16x8; 1024 waves = 1/SIMD.
// 16 launches x 8 iters; init folded into launch 0; final launch stores u only.

namespace {

typedef float v2f __attribute__((ext_vector_type(2)));

constexpr int kN = 2 * 256 * 256;
constexpr float kTau = 0.28867513459481287f;  // 1/sqrt(12) (f32)
constexpr float kSigma = kTau;
constexpr float kInv1pTau = 1.0f / (1.0f + kTau);

constexpr int HALO = 8;                  // iterations per launch
constexpr int NLAUNCH = 128 / HALO;      // 16
constexpr int LSTRIDE = 28;              // LDS row stride (floats): rows 16B-aligned
constexpr int LBUF = 32 * LSTRIDE;       // 896 floats per wave

__device__ __forceinline__ float4 ld4(const float* p) {
  return *reinterpret_cast<const float4*>(p);
}

__device__ __forceinline__ v2f mk2(float x, float y) {
  v2f r;
  r.x = x;
  r.y = y;
  return r;
}

// DPP lane shift, single VALU op. 0x130 = wave_shl:1 (lane i <- i+1),
// 0x138 = wave_shr:1 (lane i <- i-1). bound_ctrl=1 -> invalid lanes read 0.
template <int CTRL>
__device__ __forceinline__ float dppf(float x) {
  return __builtin_bit_cast(
      float, __builtin_amdgcn_update_dpp(0, __builtin_bit_cast(int, x), CTRL,
                                         0xF, 0xF, true));
}

template <int CTRL>
__device__ __forceinline__ v2f dpp2(v2f x) {
  v2f y;
  y.x = dppf<CTRL>(x.x);
  y.y = dppf<CTRL>(x.y);
  return y;
}

__device__ __forceinline__ v2f shdn(v2f x) { return dpp2<0x130>(x); }  // row r+1
__device__ __forceinline__ v2f shup(v2f x) { return dpp2<0x138>(x); }  // row r-1

// Coalesced 3x float4 load (lane covers region row-major groups l, l+64, l+128)
__device__ __forceinline__ void gload3(float4* t, const float* src,
                                       const int* goff, const bool* gok) {
#pragma unroll
  for (int i = 0; i < 3; ++i) {
    float4 z;
    z.x = 0.f; z.y = 0.f; z.z = 0.f; z.w = 0.f;
    t[i] = gok[i] ? ld4(src + goff[i]) : z;
  }
}

// LDS transpose: row-major float4 groups in -> per-lane 6 v2f column strips out.
// Intra-wave only: DS ops of one wave are in-order; no barrier needed.
__device__ __forceinline__ void transp(const float4* t, v2f* dst, float* wbuf,
                                       const int* lwoff, int lroff) {
#pragma unroll
  for (int i = 0; i < 3; ++i)
    *reinterpret_cast<float4*>(wbuf + lwoff[i]) = t[i];
#pragma unroll
  for (int c = 0; c < 6; ++c)
    dst[c] = *reinterpret_cast<const v2f*>(wbuf + lroff + 2 * c);
}

// Transposed store of the wave's 16x8 valid block (rows 8..23; half0 -> strips
// 4,5 = global cols +0..3, half1 -> strips 0,1 = global cols +4..7).
__device__ __forceinline__ void store_tr(float* dst, const v2f* s, float* wbuf,
                                         int r, int half, int lane, int sbase) {
  if (r >= 8 && r < 24) {
    float4 o;
    if (half == 0) {
      o.x = s[4].x; o.y = s[4].y; o.z = s[5].x; o.w = s[5].y;
    } else {
      o.x = s[0].x; o.y = s[0].y; o.z = s[1].x; o.w = s[1].y;
    }
    *reinterpret_cast<float4*>(wbuf + (r - 8) * 8 + half * 4) = o;
  }
  if (lane < 32) {
    const float4 o =
        *reinterpret_cast<const float4*>(wbuf + (lane >> 1) * 8 + (lane & 1) * 4);
    *reinterpret_cast<float4*>(dst + sbase) = o;
  }
}

// ws layout: 10 arrays of kN floats: ub, v1, v2, vb1, vb2, p1, p2, q11, q22, q12
__global__ __launch_bounds__(256, 1) void tgv_wave_kernel(
    const float* __restrict__ f, const float* __restrict__ rp,
    float* __restrict__ ug, float* __restrict__ ws, int t0) {
  float* ubg = ws + 0 * kN;
  float* v1g = ws + 1 * kN;
  float* v2g = ws + 2 * kN;
  float* vb1g = ws + 3 * kN;
  float* vb2g = ws + 4 * kN;
  float* p1g = ws + 5 * kN;
  float* p2g = ws + 6 * kN;
  float* q11g = ws + 7 * kN;
  float* q22g = ws + 8 * kN;
  float* q12g = ws + 9 * kN;

  __shared__ __align__(16) float smem[4 * LBUF];  // 14336 B; one buf per wave

  const int tid = threadIdx.x;
  const int wave = tid >> 6;
  const int lane = tid & 63;
  const int r = lane & 31;    // region row 0..31 (lanes!)
  const int half = lane >> 5; // column half: 0 -> cols 0..11, 1 -> cols 12..23
  float* wbuf = smem + wave * LBUF;

  const int band = blockIdx.y;               // 0..15 row band
  const int colblk = blockIdx.x * 4 + wave;  // 0..31 col block
  const int batch = blockIdx.z;

  const int row0 = band * 16 - HALO;  // region origin (row, col)
  const int col0 = colblk * 8 - HALO; // multiple of 8 (float4-aligned)

  const int gi = row0 + r;            // this lane's global row
  const int gj0 = col0 + half * 12;   // this lane's first global col

  const float alpha0 = rp[0];
  const float alpha1 = rp[1];

  // ---- transpose addressing (precomputed once) ----
  int goff[3], lwoff[3];
  bool gok[3];
#pragma unroll
  for (int i = 0; i < 3; ++i) {
    const int gidx = lane + i * 64;       // 0..191 region float4-groups
    const int rr = gidx / 6;              // region row
    const int gc = gidx - rr * 6;         // float4 group in row (cols gc*4..+3)
    const int row = row0 + rr;
    const int col = col0 + gc * 4;
    gok[i] = ((unsigned)row < 256u) && (col >= 0) && (col <= 252);
    goff[i] = batch * 65536 + row * 256 + col;
    lwoff[i] = rr * LSTRIDE + gc * 4;     // 16B-aligned (28 ≡ 0 mod 4)
  }
  const int lroff = r * LSTRIDE + half * 12;  // 8B-aligned reads
  const int sbase = batch * 65536 + (band * 16 + (lane >> 1)) * 256 +
                    colblk * 8 + (lane & 1) * 4;

  // ---- boundary masks as 0/1 multipliers ----
  const float mD = (gi != 255) ? 1.f : 0.f;  // has down neighbor
  const float mU = (gi != 0) ? 1.f : 0.f;    // has up neighbor
  v2f mR[6], mL[6];
#pragma unroll
  for (int k = 0; k < 6; ++k) {
    const int c0 = gj0 + 2 * k;
    mR[k].x = (c0 != 255) ? 1.f : 0.f;
    mR[k].y = (c0 + 1 != 255) ? 1.f : 0.f;
    mL[k].x = (c0 != 0) ? 1.f : 0.f;
    mL[k].y = 1.f;  // odd global col, never 0
  }

  // ---- per-lane state: 12 cols as 6 v2f strips per field ----
  v2f u_[6], ub_[6], v1_[6], v2_[6], vb1_[6], vb2_[6];
  v2f p1_[6], p2_[6], q11_[6], q22_[6], q12_[6], f_[6];

  if (t0 == 0) {
    float4 ta[3];
    gload3(ta, f, goff, gok);
    transp(ta, f_, wbuf, lwoff, lroff);
#pragma unroll
    for (int k = 0; k < 6; ++k) {
      u_[k] = f_[k]; ub_[k] = f_[k];
      v1_[k] = 0.f; v2_[k] = 0.f; vb1_[k] = 0.f; vb2_[k] = 0.f;
      p1_[k] = 0.f; p2_[k] = 0.f; q11_[k] = 0.f; q22_[k] = 0.f; q12_[k] = 0.f;
    }
  } else {
    // 3 groups of 4 fields: 12 float4 loads in flight per group (MLP) without
    // blowing registers; transposes bounce through the per-wave LDS buffer
    // (reuse is safe: intra-wave DS ordering + address aliasing).
    float4 ta[3], tb[3], tc[3], td[3];
    gload3(ta, f, goff, gok);
    gload3(tb, ug, goff, gok);
    gload3(tc, ubg, goff, gok);
    gload3(td, v1g, goff, gok);
    transp(ta, f_, wbuf, lwoff, lroff);
    transp(tb, u_, wbuf, lwoff, lroff);
    transp(tc, ub_, wbuf, lwoff, lroff);
    transp(td, v1_, wbuf, lwoff, lroff);
    gload3(ta, v2g, goff, gok);
    gload3(tb, vb1g, goff, gok);
    gload3(tc, vb2g, goff, gok);
    gload3(td, p1g, goff, gok);
    transp(ta, v2_, wbuf, lwoff, lroff);
    transp(tb, vb1_, wbuf, lwoff, lroff);
    transp(tc, vb2_, wbuf, lwoff, lroff);
    transp(td, p1_, wbuf, lwoff, lroff);
    gload3(ta, p2g, goff, gok);
    gload3(tb, q11g, goff, gok);
    gload3(tc, q22g, goff, gok);
    gload3(td, q12g, goff, gok);
    transp(ta, p2_, wbuf, lwoff, lroff);
    transp(tb, q11_, wbuf, lwoff, lroff);
    transp(tc, q22_, wbuf, lwoff, lroff);
    transp(td, q12_, wbuf, lwoff, lroff);
  }

#pragma unroll 1
  for (int t = 0; t < HALO; ++t) {
    // cross-half right-edge scalars (bpermute): issued here, consumed only at
    // dual strip k=5 — 5 strips (~250cyc) of independent math hide the latency
    const float ubX = __shfl_xor(ub_[0].x, 32);
    const float vb1X = __shfl_xor(vb1_[0].x, 32);
    const float vb2X = __shfl_xor(vb2_[0].x, 32);

    // ---- dual ascent + projections, strips k=0..5 ----
#pragma unroll
    for (int k = 0; k < 6; ++k) {
      const v2f ubD = shdn(ub_[k]);     // row r+1, single VALU DPP
      const v2f vb1D = shdn(vb1_[k]);
      const v2f vb2D = shdn(vb2_[k]);

      v2f ubr, vb1r, vb2r;  // right-shifted (col c+1)
      ubr.x = ub_[k].y;   ubr.y = (k < 5) ? ub_[k + 1].x : ubX;
      vb1r.x = vb1_[k].y; vb1r.y = (k < 5) ? vb1_[k + 1].x : vb1X;
      vb2r.x = vb2_[k].y; vb2r.y = (k < 5) ? vb2_[k + 1].x : vb2X;

      // p update
      const v2f du1 = mD * (ubD - ub_[k]);
      const v2f du2 = mR[k] * (ubr - ub_[k]);
      const v2f pn1 = p1_[k] + kSigma * (du1 - vb1_[k]);
      const v2f pn2 = p2_[k] + kSigma * (du2 - vb2_[k]);
      const v2f n2p = pn1 * pn1 + pn2 * pn2;
      v2f sp;
      sp.x = fminf(1.f, alpha1 * __builtin_amdgcn_rsqf(n2p.x));
      sp.y = fminf(1.f, alpha1 * __builtin_amdgcn_rsqf(n2p.y));
      p1_[k] = pn1 * sp;
      p2_[k] = pn2 * sp;

      // q update (e11, e22, e12)
      const v2f e11 = mD * (vb1D - vb1_[k]);
      const v2f e22 = mR[k] * (vb2r - vb2_[k]);
      const v2f e12 = 0.5f * (mR[k] * (vb1r - vb1_[k]) + mD * (vb2D - vb2_[k]));
      const v2f qn1 = q11_[k] + kSigma * e11;
      const v2f qn2 = q22_[k] + kSigma * e22;
      const v2f qn3 = q12_[k] + kSigma * e12;
      const v2f n2q = qn1 * qn1 + qn2 * qn2 + 2.f * (qn3 * qn3);
      v2f sq;
      sq.x = fminf(1.f, alpha0 * __builtin_amdgcn_rsqf(n2q.x));
      sq.y = fminf(1.f, alpha0 * __builtin_amdgcn_rsqf(n2q.y));
      q11_[k] = qn1 * sq;
      q22_[k] = qn2 * sq;
      q12_[k] = qn3 * sq;
    }

    // cross-half left-edge scalars (bpermute): consumed only at primal strip
    // k=0, which runs LAST below — latency hidden by 5 strips of math
    const float p2X = __shfl_xor(p2_[5].y, 32);
    const float q22X = __shfl_xor(q22_[5].y, 32);
    const float q12X = __shfl_xor(q12_[5].y, 32);

    // ---- primal descent + over-relaxation, strip order {1,2,3,4,5,0} ----
    constexpr int ord[6] = {1, 2, 3, 4, 5, 0};
#pragma unroll
    for (int kk = 0; kk < 6; ++kk) {
      const int k = ord[kk];
      const v2f p1U = shup(p1_[k]);     // row r-1, single VALU DPP
      const v2f q11U = shup(q11_[k]);
      const v2f q12U = shup(q12_[k]);

      v2f p2l, q22l, q12l;  // left-shifted (col c-1)
      p2l.x = (k > 0) ? p2_[k - 1].y : p2X;    p2l.y = p2_[k].x;
      q22l.x = (k > 0) ? q22_[k - 1].y : q22X; q22l.y = q22_[k].x;
      q12l.x = (k > 0) ? q12_[k - 1].y : q12X; q12l.y = q12_[k].x;

      const v2f divp = mD * p1_[k] + mR[k] * p2_[k] - (mU * p1U + mL[k] * p2l);
      const v2f un = (u_[k] + kTau * divp + kTau * f_[k]) * kInv1pTau;
      ub_[k] = 2.f * un - u_[k];
      u_[k] = un;

      const v2f c1 = mD * q11_[k] + mR[k] * q12_[k] - (mU * q11U + mL[k] * q12l);
      const v2f c2 = mD * q12_[k] + mR[k] * q22_[k] - (mU * q12U + mL[k] * q22l);
      const v2f v1n = v1_[k] + kTau * (p1_[k] + c1);
      const v2f v2n = v2_[k] + kTau * (p2_[k] + c2);
      vb1_[k] = 2.f * v1n - v1_[k];
      v1_[k] = v1n;
      vb2_[k] = 2.f * v2n - v2_[k];
      v2_[k] = v2n;
    }
  }

  // ---- transposed stores (coalesced 16x8 block per wave) ----
  store_tr(ug, u_, wbuf, r, half, lane, sbase);
  if (t0 != NLAUNCH - 1) {  // ws is dead after the final launch
    store_tr(ubg, ub_, wbuf, r, half, lane, sbase);
    store_tr(v1g, v1_, wbuf, r, half, lane, sbase);
    store_tr(v2g, v2_, wbuf, r, half, lane, sbase);
    store_tr(vb1g, vb1_, wbuf, r, half, lane, sbase);
    store_tr(vb2g, vb2_, wbuf, r, half, lane, sbase);
    store_tr(p1g, p1_, wbuf, r, half, lane, sbase);
    store_tr(p2g, p2_, wbuf, r, half, lane, sbase);
    store_tr(q11g, q11_, wbuf, r, half, lane, sbase);
    store_tr(q22g, q22_, wbuf, r, half, lane, sbase);
    store_tr(q12g, q12_, wbuf, r, half, lane, sbase);
  }
}

}  // namespace

extern "C" void kernel_launch(void* const* d_in, const int* in_sizes, int n_in,
                              void* d_out, int out_size, void* d_ws,
                              size_t ws_size, hipStream_t stream) {
  const float* f = (const float*)d_in[0];
  const float* rp = (const float*)d_in[1];  // [alpha0, alpha1]
  // d_in[2] is T = 128 (fixed; trip count must be static for graph capture).

  float* u = (float*)d_out;
  float* ws = (float*)d_ws;

  // 16 row-bands x 8 col-block-groups x 2 batches; 4 waves/block = 4 colblks.
  dim3 grid(8, 16, 2);  // 256 blocks, 1/CU; 1024 autonomous waves, 1/SIMD
  for (int t = 0; t < NLAUNCH; ++t) {
    hipLaunchKernelGGL(tgv_wave_kernel, grid, dim3(256), 0, stream, f, rp, u,
                       ws, t);
  }
}

// Round 6
// 296.854 us; speedup vs baseline: 1.3639x; 1.0926x over previous
//
#include <hip/hip_runtime.h>
#include <math.h>

// TGV-2 PDHG, B=2, H=W=256, T=128.
// R19: back to the R9/R14 LDS-barrier structure (253us, absmax 7.45e-9) with
// ONE structural change: 2 independent blocks per CU.
// Wave-autonomous arc (R15-R18) abandoned: at 1 wave/SIMD the body pays
// dependent-issue latency (~4cyc/op, no TLP) -> compute ~15us/dispatch, and
// occupancy can only rise by shrinking per-wave output (halo redundancy
// explodes). Best was 324us with degraded absmax (LDS transpose TBAA hazard).
// R9-family evidence: R12 (fewer DS instrs) neutral, R14 (trapezoid gating)
// neutral, R11 (6->12 waves in ONE block) +6% -> per-iter cost is the
// barrier-phase serial path, and intra-block TLP can't hide it (all waves
// march through the same phases). Untested: TWO blocks per CU. Block B has no
// barrier relationship to block A -> B issues VALU while A drains.
// Config: tile 16x16, region 32x32 (redundancy 4.0 vs R9's 3.0, +33% work),
// 512 threads = 8 waves (each wave = exactly 4 region rows), LDS 33KB/block
// -> 2 blocks/CU (66KB of 160), grid 16x16x2 = 512 blocks = 2/CU,
// __launch_bounds__(512,4) (4 waves/SIMD = 16 waves/CU = 2 blocks).
// Per-pixel math, masks, LDS exchange, I/O pattern identical to R9/R14;
// R14's validated row gating kept (freed slots now feed the other block).
// 16 launches x 8 trapezoid iters; init folded into launch 0; final launch
// stores only u.

namespace {

typedef float v2f __attribute__((ext_vector_type(2)));

constexpr int kN = 2 * 256 * 256;
constexpr float kTau = 0.28867513459481287f;  // 1/sqrt(12) (f32)
constexpr float kSigma = kTau;
constexpr float kInv1pTau = 1.0f / (1.0f + kTau);

constexpr int RR = 32;          // region rows (H)
constexpr int RC = 32;          // region cols (W)
constexpr int A = RR * RC;      // 1024 floats per LDS array
constexpr int PAD = 64;         // rim-overread safety pads (front/back)
constexpr int TILE_R = 16;
constexpr int TILE_C = 16;
constexpr int HALO = 8;         // = iterations per launch
constexpr int NLAUNCH = 128 / HALO;      // 16
constexpr int NTHREADS = RR * (RC / 2);  // 512 = 8 waves

__device__ __forceinline__ float4 ld4(const float* p) {
  return *reinterpret_cast<const float4*>(p);
}

// ws layout: 10 arrays of kN floats: ub, v1, v2, vb1, vb2, p1, p2, q11, q22, q12
__global__ __launch_bounds__(NTHREADS, 4) void tgv8_kernel(
    const float* __restrict__ f, const float* __restrict__ rp,
    float* __restrict__ ug, float* __restrict__ ws, int t0) {
  float* ubg = ws + 0 * kN;
  float* v1g = ws + 1 * kN;
  float* v2g = ws + 2 * kN;
  float* vb1g = ws + 3 * kN;
  float* vb2g = ws + 4 * kN;
  float* p1g = ws + 5 * kN;
  float* p2g = ws + 6 * kN;
  float* q11g = ws + 7 * kN;
  float* q22g = ws + 8 * kN;
  float* q12g = ws + 9 * kN;

  // LDS: ub (A) + vb-pair (2A) + p1,p2,q11,q22,q12 (5A) = 8A floats = 32KB
  __shared__ __align__(16) float smem[PAD + 8 * A + PAD];
  float* ubS = smem + PAD;
  float* vbS = ubS + A;       // interleaved [vb1, vb2] per pixel, 2A floats
  float* p1S = vbS + 2 * A;
  float* p2S = p1S + A;
  float* q11S = p2S + A;
  float* q22S = q11S + A;
  float* q12S = q22S + A;

  const int tid = threadIdx.x;
  const int r = tid >> 4;        // region row 0..31 (16 col-threads/row)
  const int c = (tid & 15) * 2;  // region col (float2-aligned)
  const int rc = r * RC + c;

  const int gi = blockIdx.y * TILE_R + r - HALO;  // global row (may be OOB)
  const int gj = blockIdx.x * TILE_C + c - HALO;  // global col (even)
  const bool inImg = ((unsigned)gi < 256u) && ((unsigned)gj < 256u);
  const int base = blockIdx.z * 65536 + gi * 256 + gj;

  const float alpha0 = rp[0];
  const float alpha1 = rp[1];

  // ---- boundary masks as 0/1 multipliers (thread-constant) ----
  const float mD = (gi != 255) ? 1.f : 0.f;  // has down neighbor (H fwd)
  const float mU = (gi != 0) ? 1.f : 0.f;    // has up neighbor (H bwd)
  v2f mR, mL;
  mR.x = (gj + 0 != 255) ? 1.f : 0.f;
  mR.y = (gj + 1 != 255) ? 1.f : 0.f;
  mL.x = (gj != 0) ? 1.f : 0.f;
  mL.y = 1.f;

  // state: one packed v2f per field
  v2f u_, ub_, v1_, v2_, vb1_, vb2_, p1_, p2_, q11_, q22_, q12_, f_;

#define LOADV(dst, src) dst = *reinterpret_cast<const v2f*>((src) + base);
  if (inImg) {
    LOADV(f_, f)
    if (t0 == 0) {
      // PDHG initial state: u = ub = f, everything else zero.
      u_ = f_; ub_ = f_;
      v1_ = 0.f; v2_ = 0.f; vb1_ = 0.f; vb2_ = 0.f;
      p1_ = 0.f; p2_ = 0.f; q11_ = 0.f; q22_ = 0.f; q12_ = 0.f;
    } else {
      LOADV(u_, ug)
      LOADV(ub_, ubg)
      LOADV(v1_, v1g)
      LOADV(v2_, v2g)
      LOADV(vb1_, vb1g)
      LOADV(vb2_, vb2g)
      LOADV(p1_, p1g)
      LOADV(p2_, p2g)
      LOADV(q11_, q11g)
      LOADV(q22_, q22g)
      LOADV(q12_, q12g)
    }
  } else {
    f_ = 0.f; u_ = 0.f; ub_ = 0.f;
    v1_ = 0.f; v2_ = 0.f; vb1_ = 0.f; vb2_ = 0.f;
    p1_ = 0.f; p2_ = 0.f; q11_ = 0.f; q22_ = 0.f; q12_ = 0.f;
  }
#undef LOADV

  for (int t = 0; t < HALO; ++t) {
    // Active-set gating (row-wise, wave-granular; waves = 4 aligned rows).
    // Rows outside the sets produce values never read by any valid pixel.
    const bool pubD = (r >= t) && (r <= 31 - t);
    const bool actD = (r >= t) && (r <= 30 - t);
    const bool actP = (r >= t + 1) && (r <= 30 - t);

    // ---- publish dual halos: ub (b64), vb pair (b128) ----
    if (pubD) {
      *reinterpret_cast<v2f*>(ubS + rc) = ub_;
      float4 vp;
      vp.x = vb1_.x; vp.y = vb2_.x; vp.z = vb1_.y; vp.w = vb2_.y;
      *reinterpret_cast<float4*>(vbS + 2 * rc) = vp;
    }
    __syncthreads();

    if (actD) {
      // ---- dual ascent + projections ----
      const float ubX = ubS[rc + 2];  // right-edge scalar neighbor
      const v2f vbX = *reinterpret_cast<const v2f*>(vbS + 2 * (rc + 2));
      const v2f ubD = *reinterpret_cast<const v2f*>(ubS + rc + RC);
      const float4 vd = ld4(vbS + 2 * (rc + RC));
      v2f vb1D, vb2D;
      vb1D.x = vd.x; vb1D.y = vd.z;
      vb2D.x = vd.y; vb2D.y = vd.w;

      v2f ubr, vb1r, vb2r;  // right-shifted (element e+1)
      ubr.x = ub_.y;   ubr.y = ubX;
      vb1r.x = vb1_.y; vb1r.y = vbX.x;
      vb2r.x = vb2_.y; vb2r.y = vbX.y;

      // p update
      const v2f du1 = mD * (ubD - ub_);
      const v2f du2 = mR * (ubr - ub_);
      const v2f pn1 = p1_ + kSigma * (du1 - vb1_);
      const v2f pn2 = p2_ + kSigma * (du2 - vb2_);
      const v2f n2p = pn1 * pn1 + pn2 * pn2;
      v2f sp;
      sp.x = fminf(1.f, alpha1 * __builtin_amdgcn_rsqf(n2p.x));
      sp.y = fminf(1.f, alpha1 * __builtin_amdgcn_rsqf(n2p.y));
      p1_ = pn1 * sp;
      p2_ = pn2 * sp;

      // q update (e11, e22, e12)
      const v2f e11 = mD * (vb1D - vb1_);
      const v2f e22 = mR * (vb2r - vb2_);
      const v2f e12 = 0.5f * (mR * (vb1r - vb1_) + mD * (vb2D - vb2_));
      const v2f qn1 = q11_ + kSigma * e11;
      const v2f qn2 = q22_ + kSigma * e22;
      const v2f qn3 = q12_ + kSigma * e12;
      const v2f n2q = qn1 * qn1 + qn2 * qn2 + 2.f * (qn3 * qn3);
      v2f sq;
      sq.x = fminf(1.f, alpha0 * __builtin_amdgcn_rsqf(n2q.x));
      sq.y = fminf(1.f, alpha0 * __builtin_amdgcn_rsqf(n2q.y));
      q11_ = qn1 * sq;
      q22_ = qn2 * sq;
      q12_ = qn3 * sq;

      // ---- publish primal halos (new p, q) ----
      *reinterpret_cast<v2f*>(p1S + rc) = p1_;
      *reinterpret_cast<v2f*>(p2S + rc) = p2_;
      *reinterpret_cast<v2f*>(q11S + rc) = q11_;
      *reinterpret_cast<v2f*>(q22S + rc) = q22_;
      *reinterpret_cast<v2f*>(q12S + rc) = q12_;
    }
    __syncthreads();

    if (actP) {
      // ---- primal descent + over-relaxation ----
      const v2f p1U = *reinterpret_cast<const v2f*>(p1S + rc - RC);
      const v2f q11U = *reinterpret_cast<const v2f*>(q11S + rc - RC);
      const v2f q12U = *reinterpret_cast<const v2f*>(q12S + rc - RC);
      const float p2Ls = p2S[rc - 1];   // left-edge scalar neighbors
      const float q22Ls = q22S[rc - 1];
      const float q12Ls = q12S[rc - 1];

      v2f p2l, q22l, q12l;  // left-shifted (element e-1)
      p2l.x = p2Ls;   p2l.y = p2_.x;
      q22l.x = q22Ls; q22l.y = q22_.x;
      q12l.x = q12Ls; q12l.y = q12_.x;

      const v2f divp = mD * p1_ + mR * p2_ - (mU * p1U + mL * p2l);
      const v2f un = (u_ + kTau * divp + kTau * f_) * kInv1pTau;
      ub_ = 2.f * un - u_;
      u_ = un;

      const v2f c1 = mD * q11_ + mR * q12_ - (mU * q11U + mL * q12l);
      const v2f c2 = mD * q12_ + mR * q22_ - (mU * q12U + mL * q22l);
      const v2f v1n = v1_ + kTau * (p1_ + c1);
      const v2f v2n = v2_ + kTau * (p2_ + c2);
      vb1_ = 2.f * v1n - v1_;
      v1_ = v1n;
      vb2_ = 2.f * v2n - v2_;
      v2_ = v2n;
    }
  }

  // ---- store interior 16x16 (exact after 8 iters) ----
  if (r >= HALO && r < HALO + TILE_R && c >= HALO && c < HALO + TILE_C) {
#define STOREV(src, dst) *reinterpret_cast<v2f*>((dst) + base) = src;
    STOREV(u_, ug)
    if (t0 != NLAUNCH - 1) {  // ws is dead after the final launch
      STOREV(ub_, ubg)
      STOREV(v1_, v1g)
      STOREV(v2_, v2g)
      STOREV(vb1_, vb1g)
      STOREV(vb2_, vb2g)
      STOREV(p1_, p1g)
      STOREV(p2_, p2g)
      STOREV(q11_, q11g)
      STOREV(q22_, q22g)
      STOREV(q12_, q12g)
    }
#undef STOREV
  }
}

}  // namespace

extern "C" void kernel_launch(void* const* d_in, const int* in_sizes, int n_in,
                              void* d_out, int out_size, void* d_ws,
                              size_t ws_size, hipStream_t stream) {
  const float* f = (const float*)d_in[0];
  const float* rp = (const float*)d_in[1];  // [alpha0, alpha1]
  // d_in[2] is T = 128 (fixed; trip count must be static for graph capture).

  float* u = (float*)d_out;
  float* ws = (float*)d_ws;

  dim3 grid(256 / TILE_C, 256 / TILE_R, 2);  // 16 x 16 x 2 = 512 blocks, 2/CU
  for (int t = 0; t < NLAUNCH; ++t) {        // 16 launches x 8 iterations
    hipLaunchKernelGGL(tgv8_kernel, grid, dim3(NTHREADS), 0, stream, f, rp, u,
                       ws, t);
  }
}

// Round 7
// 252.881 us; speedup vs baseline: 1.6010x; 1.1739x over previous
//
#include <hip/hip_runtime.h>
#include <math.h>

// TGV-2 PDHG, B=2, H=W=256, T=128.
// R20 = R14 base (best measured 253.1us, absmax 7.45e-9) + interior-block
// mask elimination + exact tau*f hoist. Model status after R11/R14/R19:
// per-iter time ~ max(issue, latency) with R9/R14 near the balance point
// (R14: -18% work -> 0%; R11: 2x TLP -> +6%; R19: +33% work -> +17%).
// This round is a discriminating probe: 66% of blocks (bx in [1,6],
// by in [1,14]) have their whole 32x48 region inside the image -> all
// boundary masks are 1.0 -> a templated maskless body removes ~18 of ~72
// packed ops/iter (25% of issue) BIT-EXACTLY (x*1.0 == x; no reassociation;
// tau*f_ hoist is the identical expression computed once). Block-uniform
// branch -> barriers legal. Issue-model predicts ~230us; max-model predicts
// neutral -> floor certified.
// Everything else identical to R14: 16 launches x 8 trapezoid iters, region
// 32x48 (tile 16x32, halo 8), 256 blocks (1/CU), 768 threads (12 waves),
// 1x2 strips, packed v_pk_f32 math, rsq+min projection, vb interleaved LDS
// pair, row-gating, init folded into launch 0, final launch stores only u.

namespace {

typedef float v2f __attribute__((ext_vector_type(2)));

constexpr int kN = 2 * 256 * 256;
constexpr float kTau = 0.28867513459481287f;  // 1/sqrt(12) (f32)
constexpr float kSigma = kTau;
constexpr float kInv1pTau = 1.0f / (1.0f + kTau);

constexpr int RR = 32;          // region rows (H)
constexpr int RC = 48;          // region cols (W)
constexpr int A = RR * RC;      // 1536 floats per LDS array
constexpr int PAD = 64;         // rim-overread safety pads (front/back)
constexpr int TILE_R = 16;
constexpr int TILE_C = 32;
constexpr int HALO = 8;         // = iterations per launch
constexpr int NLAUNCH = 128 / HALO;      // 16
constexpr int NTHREADS = RR * (RC / 2);  // 768 = 12 waves

__device__ __forceinline__ float4 ld4(const float* p) {
  return *reinterpret_cast<const float4*>(p);
}

// The 8-iteration trapezoid loop. M=true: boundary blocks (image-edge masks
// as 0/1 multipliers, exactly R14's code). M=false: interior blocks — every
// mask is 1.0, multiplies removed (bit-exact: x*1.0f == x, no reassociation).
template <bool M>
__device__ __forceinline__ void run8(
    float* ubS, float* vbS, float* p1S, float* p2S, float* q11S, float* q22S,
    float* q12S, const int rc, const int r, const float alpha0,
    const float alpha1, const float mD, const float mU, const v2f mR,
    const v2f mL, const v2f fI, v2f& u_, v2f& ub_, v2f& v1_, v2f& v2_,
    v2f& vb1_, v2f& vb2_, v2f& p1_, v2f& p2_, v2f& q11_, v2f& q22_,
    v2f& q12_) {
  for (int t = 0; t < HALO; ++t) {
    // Active-set gating (row-wise, wave-granular) — R14, measured-neutral but
    // never harmful; rows outside the sets are never read by valid outputs.
    const bool pubD = (r >= t) && (r <= 31 - t);
    const bool actD = (r >= t) && (r <= 30 - t);
    const bool actP = (r >= t + 1) && (r <= 30 - t);

    // ---- publish dual halos: ub (b64), vb pair (b128) ----
    if (pubD) {
      *reinterpret_cast<v2f*>(ubS + rc) = ub_;
      float4 vp;
      vp.x = vb1_.x; vp.y = vb2_.x; vp.z = vb1_.y; vp.w = vb2_.y;
      *reinterpret_cast<float4*>(vbS + 2 * rc) = vp;
    }
    __syncthreads();

    if (actD) {
      // ---- dual ascent + projections ----
      const float ubX = ubS[rc + 2];  // right-edge scalar neighbor
      const v2f vbX = *reinterpret_cast<const v2f*>(vbS + 2 * (rc + 2));
      const v2f ubD = *reinterpret_cast<const v2f*>(ubS + rc + RC);
      const float4 vd = ld4(vbS + 2 * (rc + RC));
      v2f vb1D, vb2D;
      vb1D.x = vd.x; vb1D.y = vd.z;
      vb2D.x = vd.y; vb2D.y = vd.w;

      v2f ubr, vb1r, vb2r;  // right-shifted (element e+1)
      ubr.x = ub_.y;   ubr.y = ubX;
      vb1r.x = vb1_.y; vb1r.y = vbX.x;
      vb2r.x = vb2_.y; vb2r.y = vbX.y;

      // p update
      const v2f du1 = M ? mD * (ubD - ub_) : (ubD - ub_);
      const v2f du2 = M ? mR * (ubr - ub_) : (ubr - ub_);
      const v2f pn1 = p1_ + kSigma * (du1 - vb1_);
      const v2f pn2 = p2_ + kSigma * (du2 - vb2_);
      const v2f n2p = pn1 * pn1 + pn2 * pn2;
      v2f sp;
      sp.x = fminf(1.f, alpha1 * __builtin_amdgcn_rsqf(n2p.x));
      sp.y = fminf(1.f, alpha1 * __builtin_amdgcn_rsqf(n2p.y));
      p1_ = pn1 * sp;
      p2_ = pn2 * sp;

      // q update (e11, e22, e12)
      const v2f e11 = M ? mD * (vb1D - vb1_) : (vb1D - vb1_);
      const v2f e22 = M ? mR * (vb2r - vb2_) : (vb2r - vb2_);
      const v2f e12 = M ? 0.5f * (mR * (vb1r - vb1_) + mD * (vb2D - vb2_))
                        : 0.5f * ((vb1r - vb1_) + (vb2D - vb2_));
      const v2f qn1 = q11_ + kSigma * e11;
      const v2f qn2 = q22_ + kSigma * e22;
      const v2f qn3 = q12_ + kSigma * e12;
      const v2f n2q = qn1 * qn1 + qn2 * qn2 + 2.f * (qn3 * qn3);
      v2f sq;
      sq.x = fminf(1.f, alpha0 * __builtin_amdgcn_rsqf(n2q.x));
      sq.y = fminf(1.f, alpha0 * __builtin_amdgcn_rsqf(n2q.y));
      q11_ = qn1 * sq;
      q22_ = qn2 * sq;
      q12_ = qn3 * sq;

      // ---- publish primal halos (new p, q) ----
      *reinterpret_cast<v2f*>(p1S + rc) = p1_;
      *reinterpret_cast<v2f*>(p2S + rc) = p2_;
      *reinterpret_cast<v2f*>(q11S + rc) = q11_;
      *reinterpret_cast<v2f*>(q22S + rc) = q22_;
      *reinterpret_cast<v2f*>(q12S + rc) = q12_;
    }
    __syncthreads();

    if (actP) {
      // ---- primal descent + over-relaxation ----
      const v2f p1U = *reinterpret_cast<const v2f*>(p1S + rc - RC);
      const v2f q11U = *reinterpret_cast<const v2f*>(q11S + rc - RC);
      const v2f q12U = *reinterpret_cast<const v2f*>(q12S + rc - RC);
      const float p2Ls = p2S[rc - 1];   // left-edge scalar neighbors
      const float q22Ls = q22S[rc - 1];
      const float q12Ls = q12S[rc - 1];

      v2f p2l, q22l, q12l;  // left-shifted (element e-1)
      p2l.x = p2Ls;   p2l.y = p2_.x;
      q22l.x = q22Ls; q22l.y = q22_.x;
      q12l.x = q12Ls; q12l.y = q12_.x;

      const v2f divp = M ? (mD * p1_ + mR * p2_ - (mU * p1U + mL * p2l))
                         : (p1_ + p2_ - (p1U + p2l));
      const v2f un = (u_ + kTau * divp + fI) * kInv1pTau;
      ub_ = 2.f * un - u_;
      u_ = un;

      const v2f c1 = M ? (mD * q11_ + mR * q12_ - (mU * q11U + mL * q12l))
                       : (q11_ + q12_ - (q11U + q12l));
      const v2f c2 = M ? (mD * q12_ + mR * q22_ - (mU * q12U + mL * q22l))
                       : (q12_ + q22_ - (q12U + q22l));
      const v2f v1n = v1_ + kTau * (p1_ + c1);
      const v2f v2n = v2_ + kTau * (p2_ + c2);
      vb1_ = 2.f * v1n - v1_;
      v1_ = v1n;
      vb2_ = 2.f * v2n - v2_;
      v2_ = v2n;
    }
  }
}

// ws layout: 10 arrays of kN floats: ub, v1, v2, vb1, vb2, p1, p2, q11, q22, q12
__global__ __launch_bounds__(NTHREADS, 3) void tgv8_kernel(
    const float* __restrict__ f, const float* __restrict__ rp,
    float* __restrict__ ug, float* __restrict__ ws, int t0) {
  float* ubg = ws + 0 * kN;
  float* v1g = ws + 1 * kN;
  float* v2g = ws + 2 * kN;
  float* vb1g = ws + 3 * kN;
  float* vb2g = ws + 4 * kN;
  float* p1g = ws + 5 * kN;
  float* p2g = ws + 6 * kN;
  float* q11g = ws + 7 * kN;
  float* q22g = ws + 8 * kN;
  float* q12g = ws + 9 * kN;

  // LDS: ub (A) + vb-pair (2A) + p1,p2,q11,q22,q12 (5A) = 8A floats
  __shared__ __align__(16) float smem[PAD + 8 * A + PAD];
  float* ubS = smem + PAD;
  float* vbS = ubS + A;       // interleaved [vb1, vb2] per pixel, 2A floats
  float* p1S = vbS + 2 * A;
  float* p2S = p1S + A;
  float* q11S = p2S + A;
  float* q22S = q11S + A;
  float* q12S = q22S + A;

  const int tid = threadIdx.x;
  const int r = tid / 24;        // region row 0..31
  const int c = (tid % 24) * 2;  // region col (float2-aligned)
  const int rc = r * RC + c;

  const int gi = blockIdx.y * TILE_R + r - HALO;  // global row (may be OOB)
  const int gj = blockIdx.x * TILE_C + c - HALO;  // global col (even)
  const bool inImg = ((unsigned)gi < 256u) && ((unsigned)gj < 256u);
  const int base = blockIdx.z * 65536 + gi * 256 + gj;

  // Interior block: whole region [by*16-8, by*16+24) x [bx*32-8, bx*32+40)
  // strictly inside (0,255) in both dims -> all masks are 1.0.
  const bool interior = (blockIdx.x >= 1) && (blockIdx.x <= 6) &&
                        (blockIdx.y >= 1) && (blockIdx.y <= 14);

  const float alpha0 = rp[0];
  const float alpha1 = rp[1];

  // ---- boundary masks as 0/1 multipliers (thread-constant) ----
  const float mD = (gi != 255) ? 1.f : 0.f;  // has down neighbor (H fwd)
  const float mU = (gi != 0) ? 1.f : 0.f;    // has up neighbor (H bwd)
  v2f mR, mL;
  mR.x = (gj + 0 != 255) ? 1.f : 0.f;
  mR.y = (gj + 1 != 255) ? 1.f : 0.f;
  mL.x = (gj != 0) ? 1.f : 0.f;
  mL.y = 1.f;

  // state: one packed v2f per field
  v2f u_, ub_, v1_, v2_, vb1_, vb2_, p1_, p2_, q11_, q22_, q12_, f_;

#define LOADV(dst, src) dst = *reinterpret_cast<const v2f*>((src) + base);
  if (inImg) {
    LOADV(f_, f)
    if (t0 == 0) {
      // PDHG initial state: u = ub = f, everything else zero.
      u_ = f_; ub_ = f_;
      v1_ = 0.f; v2_ = 0.f; vb1_ = 0.f; vb2_ = 0.f;
      p1_ = 0.f; p2_ = 0.f; q11_ = 0.f; q22_ = 0.f; q12_ = 0.f;
    } else {
      LOADV(u_, ug)
      LOADV(ub_, ubg)
      LOADV(v1_, v1g)
      LOADV(v2_, v2g)
      LOADV(vb1_, vb1g)
      LOADV(vb2_, vb2g)
      LOADV(p1_, p1g)
      LOADV(p2_, p2g)
      LOADV(q11_, q11g)
      LOADV(q22_, q22g)
      LOADV(q12_, q12g)
    }
  } else {
    f_ = 0.f; u_ = 0.f; ub_ = 0.f;
    v1_ = 0.f; v2_ = 0.f; vb1_ = 0.f; vb2_ = 0.f;
    p1_ = 0.f; p2_ = 0.f; q11_ = 0.f; q22_ = 0.f; q12_ = 0.f;
  }
#undef LOADV

  // Loop-invariant hoist (bit-exact: identical expression, computed once).
  const v2f fI = kTau * f_;

  if (interior) {
    run8<false>(ubS, vbS, p1S, p2S, q11S, q22S, q12S, rc, r, alpha0, alpha1,
                mD, mU, mR, mL, fI, u_, ub_, v1_, v2_, vb1_, vb2_, p1_, p2_,
                q11_, q22_, q12_);
  } else {
    run8<true>(ubS, vbS, p1S, p2S, q11S, q22S, q12S, rc, r, alpha0, alpha1,
               mD, mU, mR, mL, fI, u_, ub_, v1_, v2_, vb1_, vb2_, p1_, p2_,
               q11_, q22_, q12_);
  }

  // ---- store interior 16x32 (exact after 8 iters) ----
  if (r >= HALO && r < HALO + TILE_R && c >= HALO && c < HALO + TILE_C) {
#define STOREV(src, dst) *reinterpret_cast<v2f*>((dst) + base) = src;
    STOREV(u_, ug)
    if (t0 != NLAUNCH - 1) {  // ws is dead after the final launch
      STOREV(ub_, ubg)
      STOREV(v1_, v1g)
      STOREV(v2_, v2g)
      STOREV(vb1_, vb1g)
      STOREV(vb2_, vb2g)
      STOREV(p1_, p1g)
      STOREV(p2_, p2g)
      STOREV(q11_, q11g)
      STOREV(q22_, q22g)
      STOREV(q12_, q12g)
    }
#undef STOREV
  }
}

}  // namespace

extern "C" void kernel_launch(void* const* d_in, const int* in_sizes, int n_in,
                              void* d_out, int out_size, void* d_ws,
                              size_t ws_size, hipStream_t stream) {
  const float* f = (const float*)d_in[0];
  const float* rp = (const float*)d_in[1];  // [alpha0, alpha1]
  // d_in[2] is T = 128 (fixed; trip count must be static for graph capture).

  float* u = (float*)d_out;
  float* ws = (float*)d_ws;

  dim3 grid(256 / TILE_C, 256 / TILE_R, 2);  // 8 x 16 x 2 = 256 blocks
  for (int t = 0; t < NLAUNCH; ++t) {        // 16 launches x 8 iterations
    hipLaunchKernelGGL(tgv8_kernel, grid, dim3(NTHREADS), 0, stream, f, rp, u,
                       ws, t);
  }
}